// Round 2
// 994.745 us; speedup vs baseline: 1.0159x; 1.0159x over previous
//
#include <hip/hip_runtime.h>

#define ENSN 256
#define XDIM 8192
#define YD 256
#define BATCH 8

// ws layout (float offsets)
#define OFF_Y   0          // [2048][256]            Y = Ens @ H
#define OFF_YC  524288     // [8][256(y)][256(e)]    Yc (transposed, centered)
#define OFF_AUG 1048576    // [8][256][512]          [A | innov] -> [LU | M1]
#define OFF_W   2097152    // [8][256(f)][256(e)]    W = Yc^T M1 / 256
#define OFF_XM  2621440    // [8][8192]              x_m

// ---------------- K1: x_m[b][x] = mean_e Ens[b,e,x] ----------------
__global__ __launch_bounds__(256) void k1_colmean(const float* __restrict__ E,
                                                  float* __restrict__ xm) {
    int x = blockIdx.x * 256 + threadIdx.x;
    int b = blockIdx.y;
    const float* p = E + (size_t)b * ENSN * XDIM + x;
    float s = 0.f;
    #pragma unroll 8
    for (int e = 0; e < ENSN; e++) s += p[(size_t)e * XDIM];
    xm[b * XDIM + x] = s * (1.0f / ENSN);
}

// ---------------- K2: Y = E[2048x8192] @ H[8192x256] ----------------
__global__ __launch_bounds__(256) void k2_ygemm(const float* __restrict__ E,
                                                const float* __restrict__ H,
                                                float* __restrict__ Y) {
    __shared__ __align__(16) float As[16][132];
    __shared__ __align__(16) float Bs[16][68];
    int tid = threadIdx.x;
    int m0 = blockIdx.x * 128;
    int n0 = blockIdx.y * 64;
    int kb0 = blockIdx.z * 1024;
    int tr = tid >> 4, tc = tid & 15;
    float acc0[4][4], acc1[4][4];
    #pragma unroll
    for (int i = 0; i < 4; i++)
        #pragma unroll
        for (int j = 0; j < 4; j++) { acc0[i][j] = 0.f; acc1[i][j] = 0.f; }
    int er = tid >> 2, ec = (tid & 3) * 4;   // E loader: 2 rows, 4 cols each
    int hr = tid >> 4, hc = (tid & 15) * 4;  // H loader: 1 float4
    for (int kb = kb0; kb < kb0 + 1024; kb += 16) {
        float4 e0 = *(const float4*)&E[(size_t)(m0 + er) * XDIM + kb + ec];
        float4 e1 = *(const float4*)&E[(size_t)(m0 + 64 + er) * XDIM + kb + ec];
        float4 hv = *(const float4*)&H[(size_t)(kb + hr) * YD + n0 + hc];
        As[ec + 0][er] = e0.x;  As[ec + 1][er] = e0.y;
        As[ec + 2][er] = e0.z;  As[ec + 3][er] = e0.w;
        As[ec + 0][64 + er] = e1.x;  As[ec + 1][64 + er] = e1.y;
        As[ec + 2][64 + er] = e1.z;  As[ec + 3][64 + er] = e1.w;
        *(float4*)&Bs[hr][hc] = hv;
        __syncthreads();
        #pragma unroll
        for (int kk = 0; kk < 16; kk++) {
            float4 a0 = *(const float4*)&As[kk][tr * 4];
            float4 a1 = *(const float4*)&As[kk][64 + tr * 4];
            float4 bv = *(const float4*)&Bs[kk][tc * 4];
            float af0[4] = {a0.x, a0.y, a0.z, a0.w};
            float af1[4] = {a1.x, a1.y, a1.z, a1.w};
            float bf[4]  = {bv.x, bv.y, bv.z, bv.w};
            #pragma unroll
            for (int i = 0; i < 4; i++)
                #pragma unroll
                for (int j = 0; j < 4; j++) {
                    acc0[i][j] += af0[i] * bf[j];
                    acc1[i][j] += af1[i] * bf[j];
                }
        }
        __syncthreads();
    }
    #pragma unroll
    for (int i = 0; i < 4; i++)
        #pragma unroll
        for (int j = 0; j < 4; j++) {
            atomicAdd(&Y[(m0 + tr * 4 + i) * YD + n0 + tc * 4 + j], acc0[i][j]);
            atomicAdd(&Y[(m0 + 64 + tr * 4 + i) * YD + n0 + tc * 4 + j], acc1[i][j]);
        }
}

// ---------------- K3: y_m, Yc[y][e], innov -> aug right half ----------------
__global__ __launch_bounds__(256) void k3_center(const float* __restrict__ Y,
                                                 const float* __restrict__ ytm,
                                                 const float* __restrict__ ystd,
                                                 const float* __restrict__ noise,
                                                 float* __restrict__ Yc,
                                                 float* __restrict__ aug) {
    int b = blockIdx.x, tid = threadIdx.x;
    __shared__ float ym[256], tms[256], s2[256];
    __shared__ float T[64][65];
    float s = 0.f;
    for (int e = 0; e < ENSN; e++) s += Y[(b * ENSN + e) * YD + tid];
    ym[tid] = s * (1.0f / ENSN);
    tms[tid] = ytm[tid];
    float sd = ystd[tid];
    s2[tid] = sd * sd;
    __syncthreads();
    for (int y0 = 0; y0 < YD; y0 += 64)
        for (int e0 = 0; e0 < ENSN; e0 += 64) {
            int yc = tid & 63, g0 = tid >> 6;
            #pragma unroll
            for (int p = 0; p < 16; p++) {
                int er = g0 + p * 4;
                T[er][yc] = Y[(b * ENSN + e0 + er) * YD + y0 + yc];
            }
            __syncthreads();
            int ec = tid & 63;
            #pragma unroll
            for (int p = 0; p < 16; p++) {
                int yr = g0 + p * 4;
                int y = y0 + yr, e = e0 + ec;
                float yv = T[ec][yr] - ym[y];
                Yc[(size_t)b * YD * ENSN + y * ENSN + e] = yv;
                aug[(size_t)b * YD * 512 + y * 512 + 256 + e] =
                    tms[y] - yv + noise[(size_t)b * YD * ENSN + y * ENSN + e] * s2[y];
            }
            __syncthreads();
        }
}

// ---------------- K4: A = Yc Yc^T / 256 + diag(std^2) -> aug left half ----------------
__global__ __launch_bounds__(256) void k4_cyy(const float* __restrict__ Yc,
                                              const float* __restrict__ ystd,
                                              float* __restrict__ aug) {
    __shared__ float As[16][68];
    __shared__ float Bs[16][68];
    int tid = threadIdx.x;
    int m0 = blockIdx.x * 64, n0 = blockIdx.y * 64, b = blockIdx.z;
    const float* Ycb = Yc + (size_t)b * YD * ENSN;
    int tr = tid >> 4, tc = tid & 15;
    float acc[4][4];
    #pragma unroll
    for (int i = 0; i < 4; i++)
        #pragma unroll
        for (int j = 0; j < 4; j++) acc[i][j] = 0.f;
    int al = tid & 15, am0 = tid >> 4;
    for (int k0 = 0; k0 < ENSN; k0 += 16) {
        #pragma unroll
        for (int p = 0; p < 4; p++) {
            int am = am0 + p * 16;
            As[al][am] = Ycb[(m0 + am) * ENSN + k0 + al];
            Bs[al][am] = Ycb[(n0 + am) * ENSN + k0 + al];
        }
        __syncthreads();
        #pragma unroll
        for (int kk = 0; kk < 16; kk++) {
            float4 a = *(const float4*)&As[kk][tr * 4];
            float4 bb = *(const float4*)&Bs[kk][tc * 4];
            float af[4] = {a.x, a.y, a.z, a.w};
            float bf[4] = {bb.x, bb.y, bb.z, bb.w};
            #pragma unroll
            for (int i = 0; i < 4; i++)
                #pragma unroll
                for (int j = 0; j < 4; j++) acc[i][j] += af[i] * bf[j];
        }
        __syncthreads();
    }
    float* augb = aug + (size_t)b * YD * 512;
    #pragma unroll
    for (int i = 0; i < 4; i++) {
        int u = m0 + tr * 4 + i;
        #pragma unroll
        for (int j = 0; j < 4; j++) {
            int v = n0 + tc * 4 + j;
            float val = acc[i][j] * (1.0f / ENSN);
            if (u == v) { float sv = ystd[u]; val += sv * sv; }
            augb[u * 512 + v] = val;
        }
    }
}

// ---------------- K5a: per-batch LU factorization of A (left half of aug) ----------------
// grid = 8 (batch), 1024 threads. A is 256x256 in aug[b][:, 0:256] (stride 512).
// Panel solves read staged LDS copies (no dependent global loads); staging
// overlaps the serial wave0 LU; trailing update is A-only (<=224 wide).
#define RSTA 228   // U12 panel stride (max width 224); 228*4 = 16B aligned
#define LSTA 232   // L21 panel stride, layout [j][row]

__global__ __launch_bounds__(1024) void k5a_lu(float* __restrict__ aug) {
    __shared__ __align__(16) float R[32 * RSTA];    // A12 -> U12 panel [j][col]
    __shared__ __align__(16) float Ls[32 * LSTA];   // A21 -> L21 panel [j][row]
    __shared__ __align__(16) float Dg[32 * 33];
    __shared__ float invd[32];
    int b = blockIdx.x, tid = threadIdx.x;
    float* A = aug + (size_t)b * 256 * 512;
    int r5 = tid >> 5, c5 = tid & 31;

    for (int p = 0; p < 8; p++) {
        int c0 = 32 * p;
        int W2 = 224 - c0;               // trailing rows == cols (0 at p=7)
        Dg[r5 * 33 + c5] = A[(c0 + r5) * 512 + c0 + c5];
        __syncthreads();
        // wave0: in-register LU of the 32x32 diag block
        if (tid < 32) {
            float u[32];
            #pragma unroll
            for (int c = 0; c < 32; c++) u[c] = Dg[tid * 33 + c];
            for (int j = 0; j < 31; j++) {
                float pv = __shfl(u[j], j);
                float f = u[j] / pv;
                #pragma unroll
                for (int c = 0; c < 32; c++) {
                    if (c > j) {
                        float ujc = __shfl(u[c], j);
                        if (tid > j) u[c] -= f * ujc;
                    }
                }
                if (tid > j) u[j] = f;
            }
            #pragma unroll
            for (int c = 0; c < 32; c++) Dg[tid * 33 + c] = u[c];
            invd[tid] = 1.0f / u[tid];
        }
        // stage A12 and A21 panels (independent of LU -> overlaps wave0 work)
        for (int cc = c5; cc < W2; cc += 32)
            R[r5 * RSTA + cc] = A[(c0 + r5) * 512 + c0 + 32 + cc];
        for (int row = r5; row < W2; row += 32)
            Ls[c5 * LSTA + row] = A[(c0 + 32 + row) * 512 + c0 + c5];
        __syncthreads();
        // write factored diag back (L strictly-lower + U upper, both needed by k5s)
        A[(c0 + r5) * 512 + c0 + c5] = Dg[r5 * 33 + c5];
        // col-parallel: U12 = L11^-1 * A12 (from LDS)
        if (tid < W2) {
            int col = tid;
            float y[32];
            #pragma unroll
            for (int j = 0; j < 32; j++) {
                float s = R[j * RSTA + col];
                #pragma unroll
                for (int m = 0; m < 32; m++)
                    if (m < j) s -= Dg[j * 33 + m] * y[m];
                y[j] = s;
            }
            #pragma unroll
            for (int j = 0; j < 32; j++) {
                R[j * RSTA + col] = y[j];
                A[(c0 + j) * 512 + c0 + 32 + col] = y[j];
            }
        }
        // row-parallel: L21 = A21 * U11^-1 (separate waves -> runs concurrently)
        if (tid >= 512 && tid < 512 + W2) {
            int row = tid - 512;
            float l[32];
            #pragma unroll
            for (int j = 0; j < 32; j++) {
                float s = Ls[j * LSTA + row];
                #pragma unroll
                for (int m = 0; m < 32; m++)
                    if (m < j) s -= l[m] * Dg[m * 33 + j];
                l[j] = s * invd[j];
            }
            #pragma unroll
            for (int j = 0; j < 32; j++)
                Ls[j * LSTA + row] = l[j];
        }
        __syncthreads();
        if (W2 > 0) {
            // write L21 back to A (coalesced, k5s forward sweep reads it)
            for (int row = r5; row < W2; row += 32)
                A[(c0 + 32 + row) * 512 + c0 + c5] = Ls[c5 * LSTA + row];
            // trailing update: A22 -= L21 * U12 (8x8 reg tiles)
            int nct = W2 >> 3;
            int tiles = (W2 >> 3) * nct;
            for (int t = tid; t < tiles; t += 1024) {
                int rt = t / nct, ct = t - rt * nct;
                int r0 = rt << 3, cc = ct << 3;
                float* gp = A + (size_t)(c0 + 32 + r0) * 512 + c0 + 32 + cc;
                float4 acc[8][2];
                #pragma unroll
                for (int rr = 0; rr < 8; rr++) {
                    acc[rr][0] = *(float4*)(gp + rr * 512);
                    acc[rr][1] = *(float4*)(gp + rr * 512 + 4);
                }
                for (int k = 0; k < 32; k++) {
                    float4 la0 = *(const float4*)&Ls[k * LSTA + r0];
                    float4 la1 = *(const float4*)&Ls[k * LSTA + r0 + 4];
                    float4 u0  = *(const float4*)&R[k * RSTA + cc];
                    float4 u1  = *(const float4*)&R[k * RSTA + cc + 4];
                    float lv[8] = {la0.x, la0.y, la0.z, la0.w,
                                   la1.x, la1.y, la1.z, la1.w};
                    #pragma unroll
                    for (int rr = 0; rr < 8; rr++) {
                        acc[rr][0].x -= lv[rr] * u0.x;
                        acc[rr][0].y -= lv[rr] * u0.y;
                        acc[rr][0].z -= lv[rr] * u0.z;
                        acc[rr][0].w -= lv[rr] * u0.w;
                        acc[rr][1].x -= lv[rr] * u1.x;
                        acc[rr][1].y -= lv[rr] * u1.y;
                        acc[rr][1].z -= lv[rr] * u1.z;
                        acc[rr][1].w -= lv[rr] * u1.w;
                    }
                }
                #pragma unroll
                for (int rr = 0; rr < 8; rr++) {
                    *(float4*)(gp + rr * 512)     = acc[rr][0];
                    *(float4*)(gp + rr * 512 + 4) = acc[rr][1];
                }
            }
        }
        __syncthreads();
    }
}

// ---------------- K5s: fwd+bwd triangular solves, 64 RHS cols per block ----------------
// grid = (4 colblk, 8 batch) = 32 blocks, 512 threads. RHS block lives in LDS Zs
// across both sweeps (no intermediate global round-trip).
#define ZST  68
#define LBST 36

__global__ __launch_bounds__(512) void k5s_solve(float* __restrict__ aug) {
    __shared__ __align__(16) float Zs[256 * ZST];   // 69.6 KB: RHS block
    __shared__ __align__(16) float Lb[224 * LBST];  // 32.3 KB: L21 / U12 strip
    __shared__ __align__(16) float Dg[32 * 33];
    __shared__ float invd[32];
    int b = blockIdx.y, tid = threadIdx.x;
    float* A = aug + (size_t)b * 256 * 512;
    int cb = blockIdx.x * 64;
    int c = tid & 63, g = tid >> 6;       // g in 0..7
    int rr = tid >> 5, cc = tid & 31;

    // load the 256x64 RHS block
    for (int r = g; r < 256; r += 8)
        Zs[r * ZST + c] = A[r * 512 + 256 + cb + c];

    // ---- forward: L Y = Z ----
    for (int p = 0; p < 8; p++) {
        int c0 = 32 * p, nb = 224 - c0;
        for (int r = rr; r < 32; r += 16)
            Dg[r * 33 + cc] = A[(c0 + r) * 512 + c0 + cc];
        for (int r = rr; r < nb; r += 16)
            Lb[r * LBST + cc] = A[(c0 + 32 + r) * 512 + c0 + cc];
        __syncthreads();
        // 32x32 unit-lower solve, one thread per RHS column
        if (tid < 64) {
            float y[32];
            #pragma unroll
            for (int j = 0; j < 32; j++) {
                float s = Zs[(c0 + j) * ZST + tid];
                #pragma unroll
                for (int m = 0; m < 32; m++)
                    if (m < j) s -= Dg[j * 33 + m] * y[m];
                y[j] = s;
            }
            #pragma unroll
            for (int j = 0; j < 32; j++) Zs[(c0 + j) * ZST + tid] = y[j];
        }
        __syncthreads();
        if (nb > 0) {
            // panel y values for this thread's column -> registers (reused nb/8 times)
            float z[32];
            #pragma unroll
            for (int k = 0; k < 32; k++) z[k] = Zs[(c0 + k) * ZST + c];
            for (int r = g; r < nb; r += 8) {
                const float* lp = &Lb[r * LBST];
                float a0 = 0.f, a1 = 0.f, a2 = 0.f, a3 = 0.f;
                #pragma unroll
                for (int k = 0; k < 32; k += 4) {
                    float4 lv = *(const float4*)(lp + k);
                    a0 += lv.x * z[k + 0];
                    a1 += lv.y * z[k + 1];
                    a2 += lv.z * z[k + 2];
                    a3 += lv.w * z[k + 3];
                }
                Zs[(c0 + 32 + r) * ZST + c] -= (a0 + a1) + (a2 + a3);
            }
        }
        __syncthreads();
    }

    // ---- backward: U X = Y ----
    for (int p = 7; p >= 0; p--) {
        int c0 = 32 * p, na = c0;
        for (int r = rr; r < 32; r += 16)
            Dg[r * 33 + cc] = A[(c0 + r) * 512 + c0 + cc];
        for (int r = rr; r < na; r += 16)
            Lb[r * LBST + cc] = A[r * 512 + c0 + cc];
        if (tid < 32)   // diag reciprocal from global (independent of Dg staging)
            invd[tid] = 1.0f / A[(c0 + tid) * 512 + c0 + tid];
        __syncthreads();
        if (tid < 64) {
            float x[32];
            #pragma unroll
            for (int j = 31; j >= 0; j--) {
                float s = Zs[(c0 + j) * ZST + tid];
                #pragma unroll
                for (int m = 0; m < 32; m++)
                    if (m > j) s -= Dg[j * 33 + m] * x[m];
                x[j] = s * invd[j];
            }
            #pragma unroll
            for (int j = 0; j < 32; j++) Zs[(c0 + j) * ZST + tid] = x[j];
        }
        __syncthreads();
        if (na > 0) {
            float z[32];
            #pragma unroll
            for (int k = 0; k < 32; k++) z[k] = Zs[(c0 + k) * ZST + c];
            for (int r = g; r < na; r += 8) {
                const float* lp = &Lb[r * LBST];
                float a0 = 0.f, a1 = 0.f, a2 = 0.f, a3 = 0.f;
                #pragma unroll
                for (int k = 0; k < 32; k += 4) {
                    float4 lv = *(const float4*)(lp + k);
                    a0 += lv.x * z[k + 0];
                    a1 += lv.y * z[k + 1];
                    a2 += lv.z * z[k + 2];
                    a3 += lv.w * z[k + 3];
                }
                Zs[r * ZST + c] -= (a0 + a1) + (a2 + a3);
            }
        }
        __syncthreads();
    }

    // store M1 back to aug right half
    for (int r = g; r < 256; r += 8)
        A[r * 512 + 256 + cb + c] = Zs[r * ZST + c];
}

// ---------------- K6: W[f][e] = sum_y Yc[y][f] * M1[y][e] / 256 ----------------
__global__ __launch_bounds__(256) void k6_w(const float* __restrict__ Yc,
                                            const float* __restrict__ aug,
                                            float* __restrict__ W) {
    __shared__ float As[16][68];
    __shared__ float Bs[16][68];
    int tid = threadIdx.x;
    int m0 = blockIdx.x * 64, n0 = blockIdx.y * 64, b = blockIdx.z;
    const float* Ycb = Yc + (size_t)b * YD * ENSN;
    const float* augb = aug + (size_t)b * YD * 512;
    int tr = tid >> 4, tc = tid & 15;
    float acc[4][4];
    #pragma unroll
    for (int i = 0; i < 4; i++)
        #pragma unroll
        for (int j = 0; j < 4; j++) acc[i][j] = 0.f;
    int c = tid & 63, kr0 = tid >> 6;
    for (int k0 = 0; k0 < YD; k0 += 16) {
        #pragma unroll
        for (int p = 0; p < 4; p++) {
            int kk = kr0 + p * 4;
            As[kk][c] = Ycb[(k0 + kk) * ENSN + m0 + c];
            Bs[kk][c] = augb[(k0 + kk) * 512 + 256 + n0 + c];
        }
        __syncthreads();
        #pragma unroll
        for (int kk = 0; kk < 16; kk++) {
            float4 a = *(const float4*)&As[kk][tr * 4];
            float4 bb = *(const float4*)&Bs[kk][tc * 4];
            float af[4] = {a.x, a.y, a.z, a.w};
            float bf[4] = {bb.x, bb.y, bb.z, bb.w};
            #pragma unroll
            for (int i = 0; i < 4; i++)
                #pragma unroll
                for (int j = 0; j < 4; j++) acc[i][j] += af[i] * bf[j];
        }
        __syncthreads();
    }
    float* Wb = W + (size_t)b * ENSN * ENSN;
    #pragma unroll
    for (int i = 0; i < 4; i++)
        #pragma unroll
        for (int j = 0; j < 4; j++)
            Wb[(m0 + tr * 4 + i) * ENSN + n0 + tc * 4 + j] = acc[i][j] * (1.0f / ENSN);
}

// ---------------- K7: out[b,e,x] = Ens[b,e,x] + sum_f W[f][e]*(Ens[b,f,x]-x_m[b,x]) ----------------
__global__ __launch_bounds__(256) void k7_update(const float* __restrict__ E,
                                                 const float* __restrict__ W,
                                                 const float* __restrict__ xm,
                                                 float* __restrict__ out) {
    __shared__ float As[16][260];
    __shared__ float Bs[16][68];
    __shared__ float xs[64];
    int tid = threadIdx.x;
    int x0 = blockIdx.x * 64;
    int b = blockIdx.y;
    const float* Wb = W + (size_t)b * ENSN * ENSN;
    const float* Eb = E + (size_t)b * ENSN * XDIM;
    if (tid < 64) xs[tid] = xm[b * XDIM + x0 + tid];
    __syncthreads();
    int tr = tid >> 4, tc = tid & 15;
    float acc[16][4];
    #pragma unroll
    for (int i = 0; i < 16; i++)
        #pragma unroll
        for (int j = 0; j < 4; j++) acc[i][j] = 0.f;
    for (int k0 = 0; k0 < ENSN; k0 += 16) {
        #pragma unroll
        for (int p = 0; p < 16; p++)
            As[p][tid] = Wb[(k0 + p) * ENSN + tid];
        #pragma unroll
        for (int p = 0; p < 4; p++) {
            int kk = (tid >> 6) + p * 4;
            int cc = tid & 63;
            Bs[kk][cc] = Eb[(size_t)(k0 + kk) * XDIM + x0 + cc] - xs[cc];
        }
        __syncthreads();
        #pragma unroll
        for (int kk = 0; kk < 16; kk++) {
            float4 bv = *(const float4*)&Bs[kk][tc * 4];
            float bf[4] = {bv.x, bv.y, bv.z, bv.w};
            #pragma unroll
            for (int q = 0; q < 4; q++) {
                float4 av = *(const float4*)&As[kk][tr * 16 + q * 4];
                float af[4] = {av.x, av.y, av.z, av.w};
                #pragma unroll
                for (int c2 = 0; c2 < 4; c2++)
                    #pragma unroll
                    for (int j = 0; j < 4; j++)
                        acc[q * 4 + c2][j] += af[c2] * bf[j];
            }
        }
        __syncthreads();
    }
    #pragma unroll
    for (int i = 0; i < 16; i++) {
        int e = tr * 16 + i;
        size_t idx = (size_t)(b * ENSN + e) * XDIM + x0 + tc * 4;
        float4 ev = *(const float4*)&E[idx];
        float4 ov;
        ov.x = ev.x + acc[i][0];
        ov.y = ev.y + acc[i][1];
        ov.z = ev.z + acc[i][2];
        ov.w = ev.w + acc[i][3];
        *(float4*)&out[idx] = ov;
    }
}

extern "C" void kernel_launch(void* const* d_in, const int* in_sizes, int n_in,
                              void* d_out, int out_size, void* d_ws, size_t ws_size,
                              hipStream_t stream) {
    const float* Ens   = (const float*)d_in[0];  // [8,256,8192]
    const float* H     = (const float*)d_in[1];  // [8192,256]
    const float* ytm   = (const float*)d_in[2];  // [1,256]
    const float* ystd  = (const float*)d_in[3];  // [1,256]
    const float* noise = (const float*)d_in[4];  // [8,256,256]
    float* out = (float*)d_out;
    float* ws  = (float*)d_ws;

    float* Y   = ws + OFF_Y;
    float* Yc  = ws + OFF_YC;
    float* aug = ws + OFF_AUG;
    float* W   = ws + OFF_W;
    float* xm  = ws + OFF_XM;

    hipMemsetAsync(Y, 0, (size_t)2048 * 256 * sizeof(float), stream);

    k1_colmean<<<dim3(XDIM / 256, BATCH), 256, 0, stream>>>(Ens, xm);
    k2_ygemm<<<dim3(16, 4, 8), 256, 0, stream>>>(Ens, H, Y);
    k3_center<<<dim3(BATCH), 256, 0, stream>>>(Y, ytm, ystd, noise, Yc, aug);
    k4_cyy<<<dim3(4, 4, BATCH), 256, 0, stream>>>(Yc, ystd, aug);
    k5a_lu<<<dim3(BATCH), 1024, 0, stream>>>(aug);
    k5s_solve<<<dim3(4, BATCH), 512, 0, stream>>>(aug);
    k6_w<<<dim3(4, 4, BATCH), 256, 0, stream>>>(Yc, aug, W);
    k7_update<<<dim3(XDIM / 64, BATCH), 256, 0, stream>>>(Ens, W, xm, out);
}

// Round 3
// 977.231 us; speedup vs baseline: 1.0341x; 1.0179x over previous
//
#include <hip/hip_runtime.h>

#define ENSN 256
#define XDIM 8192
#define YD 256
#define BATCH 8

// ws layout (float offsets)
#define OFF_Y   0          // [2048][256]            Y = Ens @ H
#define OFF_YC  524288     // [8][256(y)][256(e)]    Yc (transposed, centered)
#define OFF_AUG 1048576    // [8][256][512]          [A | innov] -> [LU | M1]
#define OFF_W   2097152    // [8][256(f)][256(e)]    W = Yc^T M1 / 256
#define OFF_XM  2621440    // [8][8192]              x_m

// ---------------- K1: x_m[b][x] = mean_e Ens[b,e,x] ----------------
__global__ __launch_bounds__(256) void k1_colmean(const float* __restrict__ E,
                                                  float* __restrict__ xm) {
    int x = blockIdx.x * 256 + threadIdx.x;
    int b = blockIdx.y;
    const float* p = E + (size_t)b * ENSN * XDIM + x;
    float s = 0.f;
    #pragma unroll 8
    for (int e = 0; e < ENSN; e++) s += p[(size_t)e * XDIM];
    xm[b * XDIM + x] = s * (1.0f / ENSN);
}

// ---------------- K2: Y = E[2048x8192] @ H[8192x256] ----------------
// launch_bounds (256,4): 16 waves/CU -> <=128 VGPR, no accumulator spill.
__global__ __launch_bounds__(256, 4) void k2_ygemm(const float* __restrict__ E,
                                                   const float* __restrict__ H,
                                                   float* __restrict__ Y) {
    __shared__ __align__(16) float As[16][132];
    __shared__ __align__(16) float Bs[16][68];
    int tid = threadIdx.x;
    int m0 = blockIdx.x * 128;
    int n0 = blockIdx.y * 64;
    int kb0 = blockIdx.z * 1024;
    int tr = tid >> 4, tc = tid & 15;
    float acc0[4][4], acc1[4][4];
    #pragma unroll
    for (int i = 0; i < 4; i++)
        #pragma unroll
        for (int j = 0; j < 4; j++) { acc0[i][j] = 0.f; acc1[i][j] = 0.f; }
    int er = tid >> 2, ec = (tid & 3) * 4;   // E loader: 2 rows, 4 cols each
    int hr = tid >> 4, hc = (tid & 15) * 4;  // H loader: 1 float4
    for (int kb = kb0; kb < kb0 + 1024; kb += 16) {
        float4 e0 = *(const float4*)&E[(size_t)(m0 + er) * XDIM + kb + ec];
        float4 e1 = *(const float4*)&E[(size_t)(m0 + 64 + er) * XDIM + kb + ec];
        float4 hv = *(const float4*)&H[(size_t)(kb + hr) * YD + n0 + hc];
        As[ec + 0][er] = e0.x;  As[ec + 1][er] = e0.y;
        As[ec + 2][er] = e0.z;  As[ec + 3][er] = e0.w;
        As[ec + 0][64 + er] = e1.x;  As[ec + 1][64 + er] = e1.y;
        As[ec + 2][64 + er] = e1.z;  As[ec + 3][64 + er] = e1.w;
        *(float4*)&Bs[hr][hc] = hv;
        __syncthreads();
        #pragma unroll
        for (int kk = 0; kk < 16; kk++) {
            float4 a0 = *(const float4*)&As[kk][tr * 4];
            float4 a1 = *(const float4*)&As[kk][64 + tr * 4];
            float4 bv = *(const float4*)&Bs[kk][tc * 4];
            float af0[4] = {a0.x, a0.y, a0.z, a0.w};
            float af1[4] = {a1.x, a1.y, a1.z, a1.w};
            float bf[4]  = {bv.x, bv.y, bv.z, bv.w};
            #pragma unroll
            for (int i = 0; i < 4; i++)
                #pragma unroll
                for (int j = 0; j < 4; j++) {
                    acc0[i][j] += af0[i] * bf[j];
                    acc1[i][j] += af1[i] * bf[j];
                }
        }
        __syncthreads();
    }
    #pragma unroll
    for (int i = 0; i < 4; i++)
        #pragma unroll
        for (int j = 0; j < 4; j++) {
            atomicAdd(&Y[(m0 + tr * 4 + i) * YD + n0 + tc * 4 + j], acc0[i][j]);
            atomicAdd(&Y[(m0 + 64 + tr * 4 + i) * YD + n0 + tc * 4 + j], acc1[i][j]);
        }
}

// ---------------- K3: y_m, Yc[y][e], innov -> aug right half ----------------
__global__ __launch_bounds__(256) void k3_center(const float* __restrict__ Y,
                                                 const float* __restrict__ ytm,
                                                 const float* __restrict__ ystd,
                                                 const float* __restrict__ noise,
                                                 float* __restrict__ Yc,
                                                 float* __restrict__ aug) {
    int b = blockIdx.x, tid = threadIdx.x;
    __shared__ float ym[256], tms[256], s2[256];
    __shared__ float T[64][65];
    float s = 0.f;
    for (int e = 0; e < ENSN; e++) s += Y[(b * ENSN + e) * YD + tid];
    ym[tid] = s * (1.0f / ENSN);
    tms[tid] = ytm[tid];
    float sd = ystd[tid];
    s2[tid] = sd * sd;
    __syncthreads();
    for (int y0 = 0; y0 < YD; y0 += 64)
        for (int e0 = 0; e0 < ENSN; e0 += 64) {
            int yc = tid & 63, g0 = tid >> 6;
            #pragma unroll
            for (int p = 0; p < 16; p++) {
                int er = g0 + p * 4;
                T[er][yc] = Y[(b * ENSN + e0 + er) * YD + y0 + yc];
            }
            __syncthreads();
            int ec = tid & 63;
            #pragma unroll
            for (int p = 0; p < 16; p++) {
                int yr = g0 + p * 4;
                int y = y0 + yr, e = e0 + ec;
                float yv = T[ec][yr] - ym[y];
                Yc[(size_t)b * YD * ENSN + y * ENSN + e] = yv;
                aug[(size_t)b * YD * 512 + y * 512 + 256 + e] =
                    tms[y] - yv + noise[(size_t)b * YD * ENSN + y * ENSN + e] * s2[y];
            }
            __syncthreads();
        }
}

// ---------------- K4: A = Yc Yc^T / 256 + diag(std^2) -> aug left half ----------------
__global__ __launch_bounds__(256) void k4_cyy(const float* __restrict__ Yc,
                                              const float* __restrict__ ystd,
                                              float* __restrict__ aug) {
    __shared__ float As[16][68];
    __shared__ float Bs[16][68];
    int tid = threadIdx.x;
    int m0 = blockIdx.x * 64, n0 = blockIdx.y * 64, b = blockIdx.z;
    const float* Ycb = Yc + (size_t)b * YD * ENSN;
    int tr = tid >> 4, tc = tid & 15;
    float acc[4][4];
    #pragma unroll
    for (int i = 0; i < 4; i++)
        #pragma unroll
        for (int j = 0; j < 4; j++) acc[i][j] = 0.f;
    int al = tid & 15, am0 = tid >> 4;
    for (int k0 = 0; k0 < ENSN; k0 += 16) {
        #pragma unroll
        for (int p = 0; p < 4; p++) {
            int am = am0 + p * 16;
            As[al][am] = Ycb[(m0 + am) * ENSN + k0 + al];
            Bs[al][am] = Ycb[(n0 + am) * ENSN + k0 + al];
        }
        __syncthreads();
        #pragma unroll
        for (int kk = 0; kk < 16; kk++) {
            float4 a = *(const float4*)&As[kk][tr * 4];
            float4 bb = *(const float4*)&Bs[kk][tc * 4];
            float af[4] = {a.x, a.y, a.z, a.w};
            float bf[4] = {bb.x, bb.y, bb.z, bb.w};
            #pragma unroll
            for (int i = 0; i < 4; i++)
                #pragma unroll
                for (int j = 0; j < 4; j++) acc[i][j] += af[i] * bf[j];
        }
        __syncthreads();
    }
    float* augb = aug + (size_t)b * YD * 512;
    #pragma unroll
    for (int i = 0; i < 4; i++) {
        int u = m0 + tr * 4 + i;
        #pragma unroll
        for (int j = 0; j < 4; j++) {
            int v = n0 + tc * 4 + j;
            float val = acc[i][j] * (1.0f / ENSN);
            if (u == v) { float sv = ystd[u]; val += sv * sv; }
            augb[u * 512 + v] = val;
        }
    }
}

// ---------------- K5a: per-batch LU factorization of A (left half of aug) ----------------
// grid = 8 (batch), 1024 threads. launch_bounds (1024,4): 1 block/CU -> <=128
// VGPR so y[32]/l[32]/u[32] and the 4x8 trailing-tile accumulator stay in
// registers (at the default 64-VGPR cap these spilled to scratch: the serial
// solve chain then paid ~200cy/step -> the measured 264us).
#define RSTA 228   // U12 panel stride (max width 224); 228*4 = 16B aligned
#define LSTA 232   // L21 panel stride, layout [j][row]

__global__ __launch_bounds__(1024, 4) void k5a_lu(float* __restrict__ aug) {
    __shared__ __align__(16) float R[32 * RSTA];    // A12 -> U12 panel [j][col]
    __shared__ __align__(16) float Ls[32 * LSTA];   // A21 -> L21 panel [j][row]
    __shared__ __align__(16) float Dg[32 * 33];
    __shared__ float invd[32];
    int b = blockIdx.x, tid = threadIdx.x;
    float* A = aug + (size_t)b * 256 * 512;
    int r5 = tid >> 5, c5 = tid & 31;

    for (int p = 0; p < 8; p++) {
        int c0 = 32 * p;
        int W2 = 224 - c0;               // trailing rows == cols (0 at p=7)
        Dg[r5 * 33 + c5] = A[(c0 + r5) * 512 + c0 + c5];
        __syncthreads();
        // wave0: in-register LU of the 32x32 diag block
        if (tid < 32) {
            float u[32];
            #pragma unroll
            for (int c = 0; c < 32; c++) u[c] = Dg[tid * 33 + c];
            for (int j = 0; j < 31; j++) {
                float pv = __shfl(u[j], j);
                float f = u[j] / pv;
                #pragma unroll
                for (int c = 0; c < 32; c++) {
                    if (c > j) {
                        float ujc = __shfl(u[c], j);
                        if (tid > j) u[c] -= f * ujc;
                    }
                }
                if (tid > j) u[j] = f;
            }
            #pragma unroll
            for (int c = 0; c < 32; c++) Dg[tid * 33 + c] = u[c];
            invd[tid] = 1.0f / u[tid];
        }
        // stage A12 and A21 panels (independent of LU -> overlaps wave0 work)
        for (int cc = c5; cc < W2; cc += 32)
            R[r5 * RSTA + cc] = A[(c0 + r5) * 512 + c0 + 32 + cc];
        for (int row = r5; row < W2; row += 32)
            Ls[c5 * LSTA + row] = A[(c0 + 32 + row) * 512 + c0 + c5];
        __syncthreads();
        // write factored diag back (L strictly-lower + U upper, both needed by k5s)
        A[(c0 + r5) * 512 + c0 + c5] = Dg[r5 * 33 + c5];
        // col-parallel: U12 = L11^-1 * A12 (from LDS)
        if (tid < W2) {
            int col = tid;
            float y[32];
            #pragma unroll
            for (int j = 0; j < 32; j++) {
                float s = R[j * RSTA + col];
                #pragma unroll
                for (int m = 0; m < 32; m++)
                    if (m < j) s -= Dg[j * 33 + m] * y[m];
                y[j] = s;
            }
            #pragma unroll
            for (int j = 0; j < 32; j++) {
                R[j * RSTA + col] = y[j];
                A[(c0 + j) * 512 + c0 + 32 + col] = y[j];
            }
        }
        // row-parallel: L21 = A21 * U11^-1 (separate waves -> runs concurrently)
        if (tid >= 512 && tid < 512 + W2) {
            int row = tid - 512;
            float l[32];
            #pragma unroll
            for (int j = 0; j < 32; j++) {
                float s = Ls[j * LSTA + row];
                #pragma unroll
                for (int m = 0; m < 32; m++)
                    if (m < j) s -= l[m] * Dg[m * 33 + j];
                l[j] = s * invd[j];
            }
            #pragma unroll
            for (int j = 0; j < 32; j++)
                Ls[j * LSTA + row] = l[j];
        }
        __syncthreads();
        if (W2 > 0) {
            // write L21 back to A (coalesced, k5s forward sweep reads it)
            for (int row = r5; row < W2; row += 32)
                A[(c0 + 32 + row) * 512 + c0 + c5] = Ls[c5 * LSTA + row];
            // trailing update: A22 -= L21 * U12 (4x8 reg tiles; acc = 32 regs)
            int nct = W2 >> 3;
            int tiles = (W2 >> 2) * nct;
            for (int t = tid; t < tiles; t += 1024) {
                int rt = t / nct, ct = t - rt * nct;
                int r0 = rt << 2, cc = ct << 3;
                float* gp = A + (size_t)(c0 + 32 + r0) * 512 + c0 + 32 + cc;
                float4 acc[4][2];
                #pragma unroll
                for (int rr = 0; rr < 4; rr++) {
                    acc[rr][0] = *(float4*)(gp + rr * 512);
                    acc[rr][1] = *(float4*)(gp + rr * 512 + 4);
                }
                for (int k = 0; k < 32; k++) {
                    float4 la0 = *(const float4*)&Ls[k * LSTA + r0];
                    float4 u0  = *(const float4*)&R[k * RSTA + cc];
                    float4 u1  = *(const float4*)&R[k * RSTA + cc + 4];
                    float lv[4] = {la0.x, la0.y, la0.z, la0.w};
                    #pragma unroll
                    for (int rr = 0; rr < 4; rr++) {
                        acc[rr][0].x -= lv[rr] * u0.x;
                        acc[rr][0].y -= lv[rr] * u0.y;
                        acc[rr][0].z -= lv[rr] * u0.z;
                        acc[rr][0].w -= lv[rr] * u0.w;
                        acc[rr][1].x -= lv[rr] * u1.x;
                        acc[rr][1].y -= lv[rr] * u1.y;
                        acc[rr][1].z -= lv[rr] * u1.z;
                        acc[rr][1].w -= lv[rr] * u1.w;
                    }
                }
                #pragma unroll
                for (int rr = 0; rr < 4; rr++) {
                    *(float4*)(gp + rr * 512)     = acc[rr][0];
                    *(float4*)(gp + rr * 512 + 4) = acc[rr][1];
                }
            }
        }
        __syncthreads();
    }
}

// ---------------- K5s: fwd+bwd triangular solves, 64 RHS cols per block ----------------
// grid = (4 colblk, 8 batch) = 32 blocks, 512 threads. RHS block lives in LDS Zs
// across both sweeps. launch_bounds (512,2): 1 block/CU (LDS forces it anyway)
// -> <=256 VGPR so z[32]/x[32]/y[32] stay in registers.
#define ZST  68
#define LBST 36

__global__ __launch_bounds__(512, 2) void k5s_solve(float* __restrict__ aug) {
    __shared__ __align__(16) float Zs[256 * ZST];   // 69.6 KB: RHS block
    __shared__ __align__(16) float Lb[224 * LBST];  // 32.3 KB: L21 / U12 strip
    __shared__ __align__(16) float Dg[32 * 33];
    __shared__ float invd[32];
    int b = blockIdx.y, tid = threadIdx.x;
    float* A = aug + (size_t)b * 256 * 512;
    int cb = blockIdx.x * 64;
    int c = tid & 63, g = tid >> 6;       // g in 0..7
    int rr = tid >> 5, cc = tid & 31;

    // load the 256x64 RHS block
    for (int r = g; r < 256; r += 8)
        Zs[r * ZST + c] = A[r * 512 + 256 + cb + c];

    // ---- forward: L Y = Z ----
    for (int p = 0; p < 8; p++) {
        int c0 = 32 * p, nb = 224 - c0;
        for (int r = rr; r < 32; r += 16)
            Dg[r * 33 + cc] = A[(c0 + r) * 512 + c0 + cc];
        for (int r = rr; r < nb; r += 16)
            Lb[r * LBST + cc] = A[(c0 + 32 + r) * 512 + c0 + cc];
        __syncthreads();
        // 32x32 unit-lower solve, one thread per RHS column
        if (tid < 64) {
            float y[32];
            #pragma unroll
            for (int j = 0; j < 32; j++) {
                float s = Zs[(c0 + j) * ZST + tid];
                #pragma unroll
                for (int m = 0; m < 32; m++)
                    if (m < j) s -= Dg[j * 33 + m] * y[m];
                y[j] = s;
            }
            #pragma unroll
            for (int j = 0; j < 32; j++) Zs[(c0 + j) * ZST + tid] = y[j];
        }
        __syncthreads();
        if (nb > 0) {
            // panel y values for this thread's column -> registers (reused nb/8 times)
            float z[32];
            #pragma unroll
            for (int k = 0; k < 32; k++) z[k] = Zs[(c0 + k) * ZST + c];
            for (int r = g; r < nb; r += 8) {
                const float* lp = &Lb[r * LBST];
                float a0 = 0.f, a1 = 0.f, a2 = 0.f, a3 = 0.f;
                #pragma unroll
                for (int k = 0; k < 32; k += 4) {
                    float4 lv = *(const float4*)(lp + k);
                    a0 += lv.x * z[k + 0];
                    a1 += lv.y * z[k + 1];
                    a2 += lv.z * z[k + 2];
                    a3 += lv.w * z[k + 3];
                }
                Zs[(c0 + 32 + r) * ZST + c] -= (a0 + a1) + (a2 + a3);
            }
        }
        __syncthreads();
    }

    // ---- backward: U X = Y ----
    for (int p = 7; p >= 0; p--) {
        int c0 = 32 * p, na = c0;
        for (int r = rr; r < 32; r += 16)
            Dg[r * 33 + cc] = A[(c0 + r) * 512 + c0 + cc];
        for (int r = rr; r < na; r += 16)
            Lb[r * LBST + cc] = A[r * 512 + c0 + cc];
        if (tid < 32)   // diag reciprocal from global (independent of Dg staging)
            invd[tid] = 1.0f / A[(c0 + tid) * 512 + c0 + tid];
        __syncthreads();
        if (tid < 64) {
            float x[32];
            #pragma unroll
            for (int j = 31; j >= 0; j--) {
                float s = Zs[(c0 + j) * ZST + tid];
                #pragma unroll
                for (int m = 0; m < 32; m++)
                    if (m > j) s -= Dg[j * 33 + m] * x[m];
                x[j] = s * invd[j];
            }
            #pragma unroll
            for (int j = 0; j < 32; j++) Zs[(c0 + j) * ZST + tid] = x[j];
        }
        __syncthreads();
        if (na > 0) {
            float z[32];
            #pragma unroll
            for (int k = 0; k < 32; k++) z[k] = Zs[(c0 + k) * ZST + c];
            for (int r = g; r < na; r += 8) {
                const float* lp = &Lb[r * LBST];
                float a0 = 0.f, a1 = 0.f, a2 = 0.f, a3 = 0.f;
                #pragma unroll
                for (int k = 0; k < 32; k += 4) {
                    float4 lv = *(const float4*)(lp + k);
                    a0 += lv.x * z[k + 0];
                    a1 += lv.y * z[k + 1];
                    a2 += lv.z * z[k + 2];
                    a3 += lv.w * z[k + 3];
                }
                Zs[r * ZST + c] -= (a0 + a1) + (a2 + a3);
            }
        }
        __syncthreads();
    }

    // store M1 back to aug right half
    for (int r = g; r < 256; r += 8)
        A[r * 512 + 256 + cb + c] = Zs[r * ZST + c];
}

// ---------------- K6: W[f][e] = sum_y Yc[y][f] * M1[y][e] / 256 ----------------
__global__ __launch_bounds__(256) void k6_w(const float* __restrict__ Yc,
                                            const float* __restrict__ aug,
                                            float* __restrict__ W) {
    __shared__ float As[16][68];
    __shared__ float Bs[16][68];
    int tid = threadIdx.x;
    int m0 = blockIdx.x * 64, n0 = blockIdx.y * 64, b = blockIdx.z;
    const float* Ycb = Yc + (size_t)b * YD * ENSN;
    const float* augb = aug + (size_t)b * YD * 512;
    int tr = tid >> 4, tc = tid & 15;
    float acc[4][4];
    #pragma unroll
    for (int i = 0; i < 4; i++)
        #pragma unroll
        for (int j = 0; j < 4; j++) acc[i][j] = 0.f;
    int c = tid & 63, kr0 = tid >> 6;
    for (int k0 = 0; k0 < YD; k0 += 16) {
        #pragma unroll
        for (int p = 0; p < 4; p++) {
            int kk = kr0 + p * 4;
            As[kk][c] = Ycb[(k0 + kk) * ENSN + m0 + c];
            Bs[kk][c] = augb[(k0 + kk) * 512 + 256 + n0 + c];
        }
        __syncthreads();
        #pragma unroll
        for (int kk = 0; kk < 16; kk++) {
            float4 a = *(const float4*)&As[kk][tr * 4];
            float4 bb = *(const float4*)&Bs[kk][tc * 4];
            float af[4] = {a.x, a.y, a.z, a.w};
            float bf[4] = {bb.x, bb.y, bb.z, bb.w};
            #pragma unroll
            for (int i = 0; i < 4; i++)
                #pragma unroll
                for (int j = 0; j < 4; j++) acc[i][j] += af[i] * bf[j];
        }
        __syncthreads();
    }
    float* Wb = W + (size_t)b * ENSN * ENSN;
    #pragma unroll
    for (int i = 0; i < 4; i++)
        #pragma unroll
        for (int j = 0; j < 4; j++)
            Wb[(m0 + tr * 4 + i) * ENSN + n0 + tc * 4 + j] = acc[i][j] * (1.0f / ENSN);
}

// ---------------- K7: out[b,e,x] = Ens[b,e,x] + sum_f W[f][e]*(Ens[b,f,x]-x_m[b,x]) ----------------
// launch_bounds (256,4): <=128 VGPR so acc[16][4] (64 floats) stays in registers.
__global__ __launch_bounds__(256, 4) void k7_update(const float* __restrict__ E,
                                                    const float* __restrict__ W,
                                                    const float* __restrict__ xm,
                                                    float* __restrict__ out) {
    __shared__ float As[16][260];
    __shared__ float Bs[16][68];
    __shared__ float xs[64];
    int tid = threadIdx.x;
    int x0 = blockIdx.x * 64;
    int b = blockIdx.y;
    const float* Wb = W + (size_t)b * ENSN * ENSN;
    const float* Eb = E + (size_t)b * ENSN * XDIM;
    if (tid < 64) xs[tid] = xm[b * XDIM + x0 + tid];
    __syncthreads();
    int tr = tid >> 4, tc = tid & 15;
    float acc[16][4];
    #pragma unroll
    for (int i = 0; i < 16; i++)
        #pragma unroll
        for (int j = 0; j < 4; j++) acc[i][j] = 0.f;
    for (int k0 = 0; k0 < ENSN; k0 += 16) {
        #pragma unroll
        for (int p = 0; p < 16; p++)
            As[p][tid] = Wb[(k0 + p) * ENSN + tid];
        #pragma unroll
        for (int p = 0; p < 4; p++) {
            int kk = (tid >> 6) + p * 4;
            int cc = tid & 63;
            Bs[kk][cc] = Eb[(size_t)(k0 + kk) * XDIM + x0 + cc] - xs[cc];
        }
        __syncthreads();
        #pragma unroll
        for (int kk = 0; kk < 16; kk++) {
            float4 bv = *(const float4*)&Bs[kk][tc * 4];
            float bf[4] = {bv.x, bv.y, bv.z, bv.w};
            #pragma unroll
            for (int q = 0; q < 4; q++) {
                float4 av = *(const float4*)&As[kk][tr * 16 + q * 4];
                float af[4] = {av.x, av.y, av.z, av.w};
                #pragma unroll
                for (int c2 = 0; c2 < 4; c2++)
                    #pragma unroll
                    for (int j = 0; j < 4; j++)
                        acc[q * 4 + c2][j] += af[c2] * bf[j];
            }
        }
        __syncthreads();
    }
    #pragma unroll
    for (int i = 0; i < 16; i++) {
        int e = tr * 16 + i;
        size_t idx = (size_t)(b * ENSN + e) * XDIM + x0 + tc * 4;
        float4 ev = *(const float4*)&E[idx];
        float4 ov;
        ov.x = ev.x + acc[i][0];
        ov.y = ev.y + acc[i][1];
        ov.z = ev.z + acc[i][2];
        ov.w = ev.w + acc[i][3];
        *(float4*)&out[idx] = ov;
    }
}

extern "C" void kernel_launch(void* const* d_in, const int* in_sizes, int n_in,
                              void* d_out, int out_size, void* d_ws, size_t ws_size,
                              hipStream_t stream) {
    const float* Ens   = (const float*)d_in[0];  // [8,256,8192]
    const float* H     = (const float*)d_in[1];  // [8192,256]
    const float* ytm   = (const float*)d_in[2];  // [1,256]
    const float* ystd  = (const float*)d_in[3];  // [1,256]
    const float* noise = (const float*)d_in[4];  // [8,256,256]
    float* out = (float*)d_out;
    float* ws  = (float*)d_ws;

    float* Y   = ws + OFF_Y;
    float* Yc  = ws + OFF_YC;
    float* aug = ws + OFF_AUG;
    float* W   = ws + OFF_W;
    float* xm  = ws + OFF_XM;

    hipMemsetAsync(Y, 0, (size_t)2048 * 256 * sizeof(float), stream);

    k1_colmean<<<dim3(XDIM / 256, BATCH), 256, 0, stream>>>(Ens, xm);
    k2_ygemm<<<dim3(16, 4, 8), 256, 0, stream>>>(Ens, H, Y);
    k3_center<<<dim3(BATCH), 256, 0, stream>>>(Y, ytm, ystd, noise, Yc, aug);
    k4_cyy<<<dim3(4, 4, BATCH), 256, 0, stream>>>(Yc, ystd, aug);
    k5a_lu<<<dim3(BATCH), 1024, 0, stream>>>(aug);
    k5s_solve<<<dim3(4, BATCH), 512, 0, stream>>>(aug);
    k6_w<<<dim3(4, 4, BATCH), 256, 0, stream>>>(Yc, aug, W);
    k7_update<<<dim3(XDIM / 64, BATCH), 256, 0, stream>>>(Ens, W, xm, out);
}

// Round 5
// 937.873 us; speedup vs baseline: 1.0775x; 1.0420x over previous
//
#include <hip/hip_runtime.h>

#define ENSN 256
#define XDIM 8192
#define YD 256
#define BATCH 8

// ws layout (float offsets)
#define OFF_Y   0          // [2048][256]            Y = Ens @ H
#define OFF_YC  524288     // [8][256(y)][256(e)]    Yc (transposed, centered)
#define OFF_AUG 1048576    // [8][256][512]          [A | innov] -> [LU | M1]
#define OFF_W   2097152    // [8][256(f)][256(e)]    W = Yc^T M1 / 256
#define OFF_XM  2621440    // [8][8192]              x_m

// ---------------- K1: x_m[b][x] = mean_e Ens[b,e,x] ----------------
__global__ __launch_bounds__(256) void k1_colmean(const float* __restrict__ E,
                                                  float* __restrict__ xm) {
    int x = blockIdx.x * 256 + threadIdx.x;
    int b = blockIdx.y;
    const float* p = E + (size_t)b * ENSN * XDIM + x;
    float s = 0.f;
    #pragma unroll 8
    for (int e = 0; e < ENSN; e++) s += p[(size_t)e * XDIM];
    xm[b * XDIM + x] = s * (1.0f / ENSN);
}

// ---------------- K2: Y = E[2048x8192] @ H[8192x256] ----------------
__global__ __launch_bounds__(256, 4) void k2_ygemm(const float* __restrict__ E,
                                                   const float* __restrict__ H,
                                                   float* __restrict__ Y) {
    __shared__ __align__(16) float As[16][132];
    __shared__ __align__(16) float Bs[16][68];
    int tid = threadIdx.x;
    int m0 = blockIdx.x * 128;
    int n0 = blockIdx.y * 64;
    int kb0 = blockIdx.z * 1024;
    int tr = tid >> 4, tc = tid & 15;
    float acc0[4][4], acc1[4][4];
    #pragma unroll
    for (int i = 0; i < 4; i++)
        #pragma unroll
        for (int j = 0; j < 4; j++) { acc0[i][j] = 0.f; acc1[i][j] = 0.f; }
    int er = tid >> 2, ec = (tid & 3) * 4;   // E loader: 2 rows, 4 cols each
    int hr = tid >> 4, hc = (tid & 15) * 4;  // H loader: 1 float4
    for (int kb = kb0; kb < kb0 + 1024; kb += 16) {
        float4 e0 = *(const float4*)&E[(size_t)(m0 + er) * XDIM + kb + ec];
        float4 e1 = *(const float4*)&E[(size_t)(m0 + 64 + er) * XDIM + kb + ec];
        float4 hv = *(const float4*)&H[(size_t)(kb + hr) * YD + n0 + hc];
        As[ec + 0][er] = e0.x;  As[ec + 1][er] = e0.y;
        As[ec + 2][er] = e0.z;  As[ec + 3][er] = e0.w;
        As[ec + 0][64 + er] = e1.x;  As[ec + 1][64 + er] = e1.y;
        As[ec + 2][64 + er] = e1.z;  As[ec + 3][64 + er] = e1.w;
        *(float4*)&Bs[hr][hc] = hv;
        __syncthreads();
        #pragma unroll
        for (int kk = 0; kk < 16; kk++) {
            float4 a0 = *(const float4*)&As[kk][tr * 4];
            float4 a1 = *(const float4*)&As[kk][64 + tr * 4];
            float4 bv = *(const float4*)&Bs[kk][tc * 4];
            float af0[4] = {a0.x, a0.y, a0.z, a0.w};
            float af1[4] = {a1.x, a1.y, a1.z, a1.w};
            float bf[4]  = {bv.x, bv.y, bv.z, bv.w};
            #pragma unroll
            for (int i = 0; i < 4; i++)
                #pragma unroll
                for (int j = 0; j < 4; j++) {
                    acc0[i][j] += af0[i] * bf[j];
                    acc1[i][j] += af1[i] * bf[j];
                }
        }
        __syncthreads();
    }
    #pragma unroll
    for (int i = 0; i < 4; i++)
        #pragma unroll
        for (int j = 0; j < 4; j++) {
            atomicAdd(&Y[(m0 + tr * 4 + i) * YD + n0 + tc * 4 + j], acc0[i][j]);
            atomicAdd(&Y[(m0 + 64 + tr * 4 + i) * YD + n0 + tc * 4 + j], acc1[i][j]);
        }
}

// ---------------- K3: y_m, Yc[y][e], innov -> aug right half ----------------
__global__ __launch_bounds__(256) void k3_center(const float* __restrict__ Y,
                                                 const float* __restrict__ ytm,
                                                 const float* __restrict__ ystd,
                                                 const float* __restrict__ noise,
                                                 float* __restrict__ Yc,
                                                 float* __restrict__ aug) {
    int b = blockIdx.x, tid = threadIdx.x;
    __shared__ float ym[256], tms[256], s2[256];
    __shared__ float T[64][65];
    float s = 0.f;
    for (int e = 0; e < ENSN; e++) s += Y[(b * ENSN + e) * YD + tid];
    ym[tid] = s * (1.0f / ENSN);
    tms[tid] = ytm[tid];
    float sd = ystd[tid];
    s2[tid] = sd * sd;
    __syncthreads();
    for (int y0 = 0; y0 < YD; y0 += 64)
        for (int e0 = 0; e0 < ENSN; e0 += 64) {
            int yc = tid & 63, g0 = tid >> 6;
            #pragma unroll
            for (int p = 0; p < 16; p++) {
                int er = g0 + p * 4;
                T[er][yc] = Y[(b * ENSN + e0 + er) * YD + y0 + yc];
            }
            __syncthreads();
            int ec = tid & 63;
            #pragma unroll
            for (int p = 0; p < 16; p++) {
                int yr = g0 + p * 4;
                int y = y0 + yr, e = e0 + ec;
                float yv = T[ec][yr] - ym[y];
                Yc[(size_t)b * YD * ENSN + y * ENSN + e] = yv;
                aug[(size_t)b * YD * 512 + y * 512 + 256 + e] =
                    tms[y] - yv + noise[(size_t)b * YD * ENSN + y * ENSN + e] * s2[y];
            }
            __syncthreads();
        }
}

// ---------------- K4: A = Yc Yc^T / 256 + diag(std^2) -> aug left half ----------------
__global__ __launch_bounds__(256) void k4_cyy(const float* __restrict__ Yc,
                                              const float* __restrict__ ystd,
                                              float* __restrict__ aug) {
    __shared__ float As[16][68];
    __shared__ float Bs[16][68];
    int tid = threadIdx.x;
    int m0 = blockIdx.x * 64, n0 = blockIdx.y * 64, b = blockIdx.z;
    const float* Ycb = Yc + (size_t)b * YD * ENSN;
    int tr = tid >> 4, tc = tid & 15;
    float acc[4][4];
    #pragma unroll
    for (int i = 0; i < 4; i++)
        #pragma unroll
        for (int j = 0; j < 4; j++) acc[i][j] = 0.f;
    int al = tid & 15, am0 = tid >> 4;
    for (int k0 = 0; k0 < ENSN; k0 += 16) {
        #pragma unroll
        for (int p = 0; p < 4; p++) {
            int am = am0 + p * 16;
            As[al][am] = Ycb[(m0 + am) * ENSN + k0 + al];
            Bs[al][am] = Ycb[(n0 + am) * ENSN + k0 + al];
        }
        __syncthreads();
        #pragma unroll
        for (int kk = 0; kk < 16; kk++) {
            float4 a = *(const float4*)&As[kk][tr * 4];
            float4 bb = *(const float4*)&Bs[kk][tc * 4];
            float af[4] = {a.x, a.y, a.z, a.w};
            float bf[4] = {bb.x, bb.y, bb.z, bb.w};
            #pragma unroll
            for (int i = 0; i < 4; i++)
                #pragma unroll
                for (int j = 0; j < 4; j++) acc[i][j] += af[i] * bf[j];
        }
        __syncthreads();
    }
    float* augb = aug + (size_t)b * YD * 512;
    #pragma unroll
    for (int i = 0; i < 4; i++) {
        int u = m0 + tr * 4 + i;
        #pragma unroll
        for (int j = 0; j < 4; j++) {
            int v = n0 + tc * 4 + j;
            float val = acc[i][j] * (1.0f / ENSN);
            if (u == v) { float sv = ystd[u]; val += sv * sv; }
            augb[u * 512 + v] = val;
        }
    }
}

// ---------------- K5p: panel factor+solve for panel p (c0 = 32p) ----------------
// grid = 8 (batch), 1024 threads. Does: 32x32 diag LU (wave0, in-register),
// forward solve of the ENTIRE right block [A12 | Z] (width 480-c0, fuses the
// RHS forward sweep), L21 solve. Staging overlaps the serial wave0 LU.
// Trailing update moved to k5t_trail (multi-block -> uses the whole chip).
#define RSTP 484   // right-block stride (max width 480); 484*4 = 16B aligned
#define LSTP 233   // L21 stride, layout [j][row]; 233%32=9 odd -> conflict-free

__global__ __launch_bounds__(1024, 4) void k5p_panel(float* __restrict__ aug, int c0) {
    __shared__ __align__(16) float R[32 * RSTP];   // [A12 | Z] panel rows
    __shared__ float Ls[32 * LSTP];                // A21 -> L21 panel [j][row]
    __shared__ __align__(16) float Dg[32 * 33];
    __shared__ float invd[32];
    int b = blockIdx.x, tid = threadIdx.x;
    float* A = aug + (size_t)b * 256 * 512;
    int r5 = tid >> 5, c5 = tid & 31;
    int WR = 480 - c0;   // right-block width (A12 cols + 256 Z cols)
    int W2 = 224 - c0;   // sub-panel rows (0 at p=7)

    Dg[r5 * 33 + c5] = A[(c0 + r5) * 512 + c0 + c5];
    __syncthreads();
    // wave0: in-register LU of the 32x32 diag block
    if (tid < 32) {
        float u[32];
        #pragma unroll
        for (int c = 0; c < 32; c++) u[c] = Dg[tid * 33 + c];
        for (int j = 0; j < 31; j++) {
            float pv = __shfl(u[j], j);
            float f = u[j] / pv;
            #pragma unroll
            for (int c = 0; c < 32; c++) {
                if (c > j) {
                    float ujc = __shfl(u[c], j);
                    if (tid > j) u[c] -= f * ujc;
                }
            }
            if (tid > j) u[j] = f;
        }
        #pragma unroll
        for (int c = 0; c < 32; c++) Dg[tid * 33 + c] = u[c];
        invd[tid] = 1.0f / u[tid];
    }
    // stage right block + A21 panel (independent of LU -> overlaps wave0 work)
    for (int cc = c5; cc < WR; cc += 32)
        R[r5 * RSTP + cc] = A[(c0 + r5) * 512 + c0 + 32 + cc];
    for (int row = r5; row < W2; row += 32)
        Ls[c5 * LSTP + row] = A[(c0 + 32 + row) * 512 + c0 + c5];
    __syncthreads();
    // write factored diag back (L11 strictly-lower + U11; k5s reads U part)
    A[(c0 + r5) * 512 + c0 + c5] = Dg[r5 * 33 + c5];
    // col-parallel: [U12 | Y] = L11^-1 * [A12 | Z]  (threads 0..WR-1)
    if (tid < WR) {
        float y[32];
        #pragma unroll
        for (int j = 0; j < 32; j++) {
            float s = R[j * RSTP + tid];
            #pragma unroll
            for (int m = 0; m < 32; m++)
                if (m < j) s -= Dg[j * 33 + m] * y[m];
            y[j] = s;
        }
        #pragma unroll
        for (int j = 0; j < 32; j++)
            A[(c0 + j) * 512 + c0 + 32 + tid] = y[j];
    }
    // row-parallel: L21 = A21 * U11^-1  (threads 512..512+W2-1, separate waves)
    if (tid >= 512 && tid < 512 + W2) {
        int row = tid - 512;
        float l[32];
        #pragma unroll
        for (int j = 0; j < 32; j++) {
            float s = Ls[j * LSTP + row];
            #pragma unroll
            for (int m = 0; m < 32; m++)
                if (m < j) s -= l[m] * Dg[m * 33 + j];
            l[j] = s * invd[j];
        }
        #pragma unroll
        for (int j = 0; j < 32; j++)
            Ls[j * LSTP + row] = l[j];
    }
    __syncthreads();
    // L21 writeback (coalesced)
    for (int row = r5; row < W2; row += 32)
        A[(c0 + 32 + row) * 512 + c0 + c5] = Ls[c5 * LSTP + row];
}

// ---------------- K5t: trailing update [A22|Z] -= L21 * [U12|Y] ----------------
// grid = (7-p, 15-p, 8), 256 threads, 32x32 output tile, K=32. Fully parallel:
// spreads the FLOP bulk of the factorization over up to 840 blocks.
__global__ __launch_bounds__(256) void k5t_trail(float* __restrict__ aug, int c0) {
    __shared__ __align__(16) float Lt[32][36];
    __shared__ __align__(16) float Ut[32][36];
    int b = blockIdx.z, tid = threadIdx.x;
    float* A = aug + (size_t)b * 256 * 512;
    int r0  = c0 + 32 + blockIdx.x * 32;
    int cc0 = c0 + 32 + blockIdx.y * 32;
    int lr = tid >> 3, lc = (tid & 7) * 4;
    *(float4*)&Lt[lr][lc] = *(const float4*)&A[(size_t)(r0 + lr) * 512 + c0 + lc];
    *(float4*)&Ut[lr][lc] = *(const float4*)&A[(size_t)(c0 + lr) * 512 + cc0 + lc];
    __syncthreads();
    float* gp = &A[(size_t)(r0 + lr) * 512 + cc0 + lc];
    float4 acc = *(const float4*)gp;
    #pragma unroll
    for (int k = 0; k < 32; k++) {
        float lv = Lt[lr][k];
        float4 uv = *(const float4*)&Ut[k][lc];
        acc.x -= lv * uv.x;
        acc.y -= lv * uv.y;
        acc.z -= lv * uv.z;
        acc.w -= lv * uv.w;
    }
    *(float4*)gp = acc;
}

// ---------------- K5s: BACKWARD substitution only (U X = Y), 64 cols/block ----------------
// grid = (4 colblk, 8 batch) = 32 blocks, 512 threads. Forward sweep is now
// fused into k5p/k5t, so Z already holds Y on entry.
#define ZST  68
#define LBST 36

__global__ __launch_bounds__(512, 2) void k5s_solve(float* __restrict__ aug) {
    __shared__ __align__(16) float Zs[256 * ZST];   // 69.6 KB: RHS block
    __shared__ __align__(16) float Lb[224 * LBST];  // 32.3 KB: U strip above
    __shared__ __align__(16) float Dg[32 * 33];
    __shared__ float invd[32];
    int b = blockIdx.y, tid = threadIdx.x;
    float* A = aug + (size_t)b * 256 * 512;
    int cb = blockIdx.x * 64;
    int c = tid & 63, g = tid >> 6;       // g in 0..7
    int rr = tid >> 5, cc = tid & 31;

    // load the 256x64 Y block
    for (int r = g; r < 256; r += 8)
        Zs[r * ZST + c] = A[r * 512 + 256 + cb + c];

    for (int p = 7; p >= 0; p--) {
        int c0 = 32 * p, na = c0;
        for (int r = rr; r < 32; r += 16)
            Dg[r * 33 + cc] = A[(c0 + r) * 512 + c0 + cc];
        for (int r = rr; r < na; r += 16)
            Lb[r * LBST + cc] = A[r * 512 + c0 + cc];
        if (tid < 32)   // diag reciprocal from global (independent of Dg staging)
            invd[tid] = 1.0f / A[(c0 + tid) * 512 + c0 + tid];
        __syncthreads();
        // 32x32 upper back-solve, one thread per RHS column
        if (tid < 64) {
            float x[32];
            #pragma unroll
            for (int j = 31; j >= 0; j--) {
                float s = Zs[(c0 + j) * ZST + tid];
                #pragma unroll
                for (int m = 0; m < 32; m++)
                    if (m > j) s -= Dg[j * 33 + m] * x[m];
                x[j] = s * invd[j];
            }
            #pragma unroll
            for (int j = 0; j < 32; j++) Zs[(c0 + j) * ZST + tid] = x[j];
        }
        __syncthreads();
        if (na > 0) {
            // panel x values for this thread's column -> registers
            float z[32];
            #pragma unroll
            for (int k = 0; k < 32; k++) z[k] = Zs[(c0 + k) * ZST + c];
            for (int r = g; r < na; r += 8) {
                const float* lp = &Lb[r * LBST];
                float a0 = 0.f, a1 = 0.f, a2 = 0.f, a3 = 0.f;
                #pragma unroll
                for (int k = 0; k < 32; k += 4) {
                    float4 lv = *(const float4*)(lp + k);
                    a0 += lv.x * z[k + 0];
                    a1 += lv.y * z[k + 1];
                    a2 += lv.z * z[k + 2];
                    a3 += lv.w * z[k + 3];
                }
                Zs[r * ZST + c] -= (a0 + a1) + (a2 + a3);
            }
        }
        __syncthreads();
    }

    // store M1 back to aug right half
    for (int r = g; r < 256; r += 8)
        A[r * 512 + 256 + cb + c] = Zs[r * ZST + c];
}

// ---------------- K6: W[f][e] = sum_y Yc[y][f] * M1[y][e] / 256 ----------------
__global__ __launch_bounds__(256) void k6_w(const float* __restrict__ Yc,
                                            const float* __restrict__ aug,
                                            float* __restrict__ W) {
    __shared__ float As[16][68];
    __shared__ float Bs[16][68];
    int tid = threadIdx.x;
    int m0 = blockIdx.x * 64, n0 = blockIdx.y * 64, b = blockIdx.z;
    const float* Ycb = Yc + (size_t)b * YD * ENSN;
    const float* augb = aug + (size_t)b * YD * 512;
    int tr = tid >> 4, tc = tid & 15;
    float acc[4][4];
    #pragma unroll
    for (int i = 0; i < 4; i++)
        #pragma unroll
        for (int j = 0; j < 4; j++) acc[i][j] = 0.f;
    int c = tid & 63, kr0 = tid >> 6;
    for (int k0 = 0; k0 < YD; k0 += 16) {
        #pragma unroll
        for (int p = 0; p < 4; p++) {
            int kk = kr0 + p * 4;
            As[kk][c] = Ycb[(k0 + kk) * ENSN + m0 + c];
            Bs[kk][c] = augb[(k0 + kk) * 512 + 256 + n0 + c];
        }
        __syncthreads();
        #pragma unroll
        for (int kk = 0; kk < 16; kk++) {
            float4 a = *(const float4*)&As[kk][tr * 4];
            float4 bb = *(const float4*)&Bs[kk][tc * 4];
            float af[4] = {a.x, a.y, a.z, a.w};
            float bf[4] = {bb.x, bb.y, bb.z, bb.w};
            #pragma unroll
            for (int i = 0; i < 4; i++)
                #pragma unroll
                for (int j = 0; j < 4; j++) acc[i][j] += af[i] * bf[j];
        }
        __syncthreads();
    }
    float* Wb = W + (size_t)b * ENSN * ENSN;
    #pragma unroll
    for (int i = 0; i < 4; i++)
        #pragma unroll
        for (int j = 0; j < 4; j++)
            Wb[(m0 + tr * 4 + i) * ENSN + n0 + tc * 4 + j] = acc[i][j] * (1.0f / ENSN);
}

// ---------------- K7: out[b,e,x] = Ens[b,e,x] + sum_f W[f][e]*(Ens[b,f,x]-x_m[b,x]) ----------------
__global__ __launch_bounds__(256, 4) void k7_update(const float* __restrict__ E,
                                                    const float* __restrict__ W,
                                                    const float* __restrict__ xm,
                                                    float* __restrict__ out) {
    __shared__ float As[16][260];
    __shared__ float Bs[16][68];
    __shared__ float xs[64];
    int tid = threadIdx.x;
    int x0 = blockIdx.x * 64;
    int b = blockIdx.y;
    const float* Wb = W + (size_t)b * ENSN * ENSN;
    const float* Eb = E + (size_t)b * ENSN * XDIM;
    if (tid < 64) xs[tid] = xm[b * XDIM + x0 + tid];
    __syncthreads();
    int tr = tid >> 4, tc = tid & 15;
    float acc[16][4];
    #pragma unroll
    for (int i = 0; i < 16; i++)
        #pragma unroll
        for (int j = 0; j < 4; j++) acc[i][j] = 0.f;
    for (int k0 = 0; k0 < ENSN; k0 += 16) {
        #pragma unroll
        for (int p = 0; p < 16; p++)
            As[p][tid] = Wb[(k0 + p) * ENSN + tid];
        #pragma unroll
        for (int p = 0; p < 4; p++) {
            int kk = (tid >> 6) + p * 4;
            int cc = tid & 63;
            Bs[kk][cc] = Eb[(size_t)(k0 + kk) * XDIM + x0 + cc] - xs[cc];
        }
        __syncthreads();
        #pragma unroll
        for (int kk = 0; kk < 16; kk++) {
            float4 bv = *(const float4*)&Bs[kk][tc * 4];
            float bf[4] = {bv.x, bv.y, bv.z, bv.w};
            #pragma unroll
            for (int q = 0; q < 4; q++) {
                float4 av = *(const float4*)&As[kk][tr * 16 + q * 4];
                float af[4] = {av.x, av.y, av.z, av.w};
                #pragma unroll
                for (int c2 = 0; c2 < 4; c2++)
                    #pragma unroll
                    for (int j = 0; j < 4; j++)
                        acc[q * 4 + c2][j] += af[c2] * bf[j];
            }
        }
        __syncthreads();
    }
    #pragma unroll
    for (int i = 0; i < 16; i++) {
        int e = tr * 16 + i;
        size_t idx = (size_t)(b * ENSN + e) * XDIM + x0 + tc * 4;
        float4 ev = *(const float4*)&E[idx];
        float4 ov;
        ov.x = ev.x + acc[i][0];
        ov.y = ev.y + acc[i][1];
        ov.z = ev.z + acc[i][2];
        ov.w = ev.w + acc[i][3];
        *(float4*)&out[idx] = ov;
    }
}

extern "C" void kernel_launch(void* const* d_in, const int* in_sizes, int n_in,
                              void* d_out, int out_size, void* d_ws, size_t ws_size,
                              hipStream_t stream) {
    const float* Ens   = (const float*)d_in[0];  // [8,256,8192]
    const float* H     = (const float*)d_in[1];  // [8192,256]
    const float* ytm   = (const float*)d_in[2];  // [1,256]
    const float* ystd  = (const float*)d_in[3];  // [1,256]
    const float* noise = (const float*)d_in[4];  // [8,256,256]
    float* out = (float*)d_out;
    float* ws  = (float*)d_ws;

    float* Y   = ws + OFF_Y;
    float* Yc  = ws + OFF_YC;
    float* aug = ws + OFF_AUG;
    float* W   = ws + OFF_W;
    float* xm  = ws + OFF_XM;

    hipMemsetAsync(Y, 0, (size_t)2048 * 256 * sizeof(float), stream);

    k1_colmean<<<dim3(XDIM / 256, BATCH), 256, 0, stream>>>(Ens, xm);
    k2_ygemm<<<dim3(16, 4, 8), 256, 0, stream>>>(Ens, H, Y);
    k3_center<<<dim3(BATCH), 256, 0, stream>>>(Y, ytm, ystd, noise, Yc, aug);
    k4_cyy<<<dim3(4, 4, BATCH), 256, 0, stream>>>(Yc, ystd, aug);
    for (int p = 0; p < 8; p++) {
        k5p_panel<<<dim3(BATCH), 1024, 0, stream>>>(aug, 32 * p);
        if (p < 7)
            k5t_trail<<<dim3(7 - p, 15 - p, BATCH), 256, 0, stream>>>(aug, 32 * p);
    }
    k5s_solve<<<dim3(4, BATCH), 512, 0, stream>>>(aug);
    k6_w<<<dim3(4, 4, BATCH), 256, 0, stream>>>(Yc, aug, W);
    k7_update<<<dim3(XDIM / 64, BATCH), 256, 0, stream>>>(Ens, W, xm, out);
}

// Round 6
// 847.752 us; speedup vs baseline: 1.1920x; 1.1063x over previous
//
#include <hip/hip_runtime.h>

#define ENSN 256
#define XDIM 8192
#define YD 256
#define BATCH 8

// ws layout (float offsets)
#define OFF_Y   0          // [2048][256]            Y = Ens @ H
#define OFF_YC  524288     // [8][256(y)][256(e)]    Yc (transposed, centered)
#define OFF_AUG 1048576    // [8][256][512]          [A | innov] -> [LU | M1]
#define OFF_W   2097152    // [8][256(f)][256(e)]    W = Yc^T M1 / 256
#define OFF_XM  2621440    // [8][8192]              x_m

// ---------------- K1: x_m[b][x] = mean_e Ens[b,e,x] ----------------
__global__ __launch_bounds__(256) void k1_colmean(const float* __restrict__ E,
                                                  float* __restrict__ xm) {
    int x = blockIdx.x * 256 + threadIdx.x;
    int b = blockIdx.y;
    const float* p = E + (size_t)b * ENSN * XDIM + x;
    float s = 0.f;
    #pragma unroll 8
    for (int e = 0; e < ENSN; e++) s += p[(size_t)e * XDIM];
    xm[b * XDIM + x] = s * (1.0f / ENSN);
}

// ---------------- K2: Y = E[2048x8192] @ H[8192x256] ----------------
// split-K=16: grid (16,4,16) = 1024 blocks -> 4 blocks/CU, 16 waves/CU.
// (At split-K=8 the grid capped occupancy at 2 blocks/CU: Occupancy 19%,
// VALUBusy 37%, latency-bound. More waves hide the single-buffer barriers.)
#define K2SPLIT 16
#define K2KLEN  (XDIM / K2SPLIT)   // 512

__global__ __launch_bounds__(256, 4) void k2_ygemm(const float* __restrict__ E,
                                                   const float* __restrict__ H,
                                                   float* __restrict__ Y) {
    __shared__ __align__(16) float As[16][132];
    __shared__ __align__(16) float Bs[16][68];
    int tid = threadIdx.x;
    int m0 = blockIdx.x * 128;
    int n0 = blockIdx.y * 64;
    int kb0 = blockIdx.z * K2KLEN;
    int tr = tid >> 4, tc = tid & 15;
    float acc0[4][4], acc1[4][4];
    #pragma unroll
    for (int i = 0; i < 4; i++)
        #pragma unroll
        for (int j = 0; j < 4; j++) { acc0[i][j] = 0.f; acc1[i][j] = 0.f; }
    int er = tid >> 2, ec = (tid & 3) * 4;   // E loader: 2 rows, 4 cols each
    int hr = tid >> 4, hc = (tid & 15) * 4;  // H loader: 1 float4
    for (int kb = kb0; kb < kb0 + K2KLEN; kb += 16) {
        float4 e0 = *(const float4*)&E[(size_t)(m0 + er) * XDIM + kb + ec];
        float4 e1 = *(const float4*)&E[(size_t)(m0 + 64 + er) * XDIM + kb + ec];
        float4 hv = *(const float4*)&H[(size_t)(kb + hr) * YD + n0 + hc];
        As[ec + 0][er] = e0.x;  As[ec + 1][er] = e0.y;
        As[ec + 2][er] = e0.z;  As[ec + 3][er] = e0.w;
        As[ec + 0][64 + er] = e1.x;  As[ec + 1][64 + er] = e1.y;
        As[ec + 2][64 + er] = e1.z;  As[ec + 3][64 + er] = e1.w;
        *(float4*)&Bs[hr][hc] = hv;
        __syncthreads();
        #pragma unroll
        for (int kk = 0; kk < 16; kk++) {
            float4 a0 = *(const float4*)&As[kk][tr * 4];
            float4 a1 = *(const float4*)&As[kk][64 + tr * 4];
            float4 bv = *(const float4*)&Bs[kk][tc * 4];
            float af0[4] = {a0.x, a0.y, a0.z, a0.w};
            float af1[4] = {a1.x, a1.y, a1.z, a1.w};
            float bf[4]  = {bv.x, bv.y, bv.z, bv.w};
            #pragma unroll
            for (int i = 0; i < 4; i++)
                #pragma unroll
                for (int j = 0; j < 4; j++) {
                    acc0[i][j] += af0[i] * bf[j];
                    acc1[i][j] += af1[i] * bf[j];
                }
        }
        __syncthreads();
    }
    #pragma unroll
    for (int i = 0; i < 4; i++)
        #pragma unroll
        for (int j = 0; j < 4; j++) {
            atomicAdd(&Y[(m0 + tr * 4 + i) * YD + n0 + tc * 4 + j], acc0[i][j]);
            atomicAdd(&Y[(m0 + 64 + tr * 4 + i) * YD + n0 + tc * 4 + j], acc1[i][j]);
        }
}

// ---------------- K3: y_m, Yc[y][e], innov -> aug right half ----------------
// grid (4 y-stripes, 8 batch) = 32 blocks (was 8 -> starved 3% of the chip).
// Per block: 64 y-columns; 4-way partial reduce for ym, then 4 transpose tiles.
__global__ __launch_bounds__(256) void k3_center(const float* __restrict__ Y,
                                                 const float* __restrict__ ytm,
                                                 const float* __restrict__ ystd,
                                                 const float* __restrict__ noise,
                                                 float* __restrict__ Yc,
                                                 float* __restrict__ aug) {
    int b = blockIdx.y, tid = threadIdx.x;
    int y0 = blockIdx.x * 64;
    __shared__ float red[4][64];
    __shared__ float ym[64], tms[64], s2[64];
    __shared__ float T[64][65];
    int yl = tid & 63, q = tid >> 6;      // q in 0..3
    // partial column sums over this thread's e-quarter (coalesced in yl)
    float s = 0.f;
    for (int e = q * 64; e < q * 64 + 64; e++)
        s += Y[(size_t)(b * ENSN + e) * YD + y0 + yl];
    red[q][yl] = s;
    __syncthreads();
    if (tid < 64) {
        ym[tid] = (red[0][tid] + red[1][tid] + red[2][tid] + red[3][tid]) * (1.0f / ENSN);
        float sd = ystd[y0 + tid];
        s2[tid] = sd * sd;
        tms[tid] = ytm[y0 + tid];
    }
    __syncthreads();
    for (int e0 = 0; e0 < ENSN; e0 += 64) {
        #pragma unroll
        for (int p = 0; p < 16; p++) {
            int er = q + p * 4;
            T[er][yl] = Y[(size_t)(b * ENSN + e0 + er) * YD + y0 + yl];
        }
        __syncthreads();
        int ec = yl;
        #pragma unroll
        for (int p = 0; p < 16; p++) {
            int yr = q + p * 4;
            int y = y0 + yr, e = e0 + ec;
            float yv = T[ec][yr] - ym[yr];
            Yc[(size_t)b * YD * ENSN + (size_t)y * ENSN + e] = yv;
            aug[(size_t)b * YD * 512 + (size_t)y * 512 + 256 + e] =
                tms[yr] - yv + noise[(size_t)b * YD * ENSN + (size_t)y * ENSN + e] * s2[yr];
        }
        __syncthreads();
    }
}

// ---------------- K4: A = Yc Yc^T / 256 + diag(std^2) -> aug left half ----------------
__global__ __launch_bounds__(256) void k4_cyy(const float* __restrict__ Yc,
                                              const float* __restrict__ ystd,
                                              float* __restrict__ aug) {
    __shared__ float As[16][68];
    __shared__ float Bs[16][68];
    int tid = threadIdx.x;
    int m0 = blockIdx.x * 64, n0 = blockIdx.y * 64, b = blockIdx.z;
    const float* Ycb = Yc + (size_t)b * YD * ENSN;
    int tr = tid >> 4, tc = tid & 15;
    float acc[4][4];
    #pragma unroll
    for (int i = 0; i < 4; i++)
        #pragma unroll
        for (int j = 0; j < 4; j++) acc[i][j] = 0.f;
    int al = tid & 15, am0 = tid >> 4;
    for (int k0 = 0; k0 < ENSN; k0 += 16) {
        #pragma unroll
        for (int p = 0; p < 4; p++) {
            int am = am0 + p * 16;
            As[al][am] = Ycb[(m0 + am) * ENSN + k0 + al];
            Bs[al][am] = Ycb[(n0 + am) * ENSN + k0 + al];
        }
        __syncthreads();
        #pragma unroll
        for (int kk = 0; kk < 16; kk++) {
            float4 a = *(const float4*)&As[kk][tr * 4];
            float4 bb = *(const float4*)&Bs[kk][tc * 4];
            float af[4] = {a.x, a.y, a.z, a.w};
            float bf[4] = {bb.x, bb.y, bb.z, bb.w};
            #pragma unroll
            for (int i = 0; i < 4; i++)
                #pragma unroll
                for (int j = 0; j < 4; j++) acc[i][j] += af[i] * bf[j];
        }
        __syncthreads();
    }
    float* augb = aug + (size_t)b * YD * 512;
    #pragma unroll
    for (int i = 0; i < 4; i++) {
        int u = m0 + tr * 4 + i;
        #pragma unroll
        for (int j = 0; j < 4; j++) {
            int v = n0 + tc * 4 + j;
            float val = acc[i][j] * (1.0f / ENSN);
            if (u == v) { float sv = ystd[u]; val += sv * sv; }
            augb[u * 512 + v] = val;
        }
    }
}

// ---------------- K5p: panel factor+solve for panel p (c0 = 32p) ----------------
#define RSTP 484   // right-block stride (max width 480); 484*4 = 16B aligned
#define LSTP 233   // L21 stride, layout [j][row]; 233%32=9 odd -> conflict-free

__global__ __launch_bounds__(1024, 4) void k5p_panel(float* __restrict__ aug, int c0) {
    __shared__ __align__(16) float R[32 * RSTP];   // [A12 | Z] panel rows
    __shared__ float Ls[32 * LSTP];                // A21 -> L21 panel [j][row]
    __shared__ __align__(16) float Dg[32 * 33];
    __shared__ float invd[32];
    int b = blockIdx.x, tid = threadIdx.x;
    float* A = aug + (size_t)b * 256 * 512;
    int r5 = tid >> 5, c5 = tid & 31;
    int WR = 480 - c0;   // right-block width (A12 cols + 256 Z cols)
    int W2 = 224 - c0;   // sub-panel rows (0 at p=7)

    Dg[r5 * 33 + c5] = A[(c0 + r5) * 512 + c0 + c5];
    __syncthreads();
    // wave0: in-register LU of the 32x32 diag block
    if (tid < 32) {
        float u[32];
        #pragma unroll
        for (int c = 0; c < 32; c++) u[c] = Dg[tid * 33 + c];
        for (int j = 0; j < 31; j++) {
            float pv = __shfl(u[j], j);
            float f = u[j] / pv;
            #pragma unroll
            for (int c = 0; c < 32; c++) {
                if (c > j) {
                    float ujc = __shfl(u[c], j);
                    if (tid > j) u[c] -= f * ujc;
                }
            }
            if (tid > j) u[j] = f;
        }
        #pragma unroll
        for (int c = 0; c < 32; c++) Dg[tid * 33 + c] = u[c];
        invd[tid] = 1.0f / u[tid];
    }
    // stage right block + A21 panel (independent of LU -> overlaps wave0 work)
    for (int cc = c5; cc < WR; cc += 32)
        R[r5 * RSTP + cc] = A[(c0 + r5) * 512 + c0 + 32 + cc];
    for (int row = r5; row < W2; row += 32)
        Ls[c5 * LSTP + row] = A[(c0 + 32 + row) * 512 + c0 + c5];
    __syncthreads();
    // write factored diag back (L11 strictly-lower + U11; k5s reads U part)
    A[(c0 + r5) * 512 + c0 + c5] = Dg[r5 * 33 + c5];
    // col-parallel: [U12 | Y] = L11^-1 * [A12 | Z]  (threads 0..WR-1)
    if (tid < WR) {
        float y[32];
        #pragma unroll
        for (int j = 0; j < 32; j++) {
            float s = R[j * RSTP + tid];
            #pragma unroll
            for (int m = 0; m < 32; m++)
                if (m < j) s -= Dg[j * 33 + m] * y[m];
            y[j] = s;
        }
        #pragma unroll
        for (int j = 0; j < 32; j++)
            A[(c0 + j) * 512 + c0 + 32 + tid] = y[j];
    }
    // row-parallel: L21 = A21 * U11^-1  (threads 512..512+W2-1, separate waves)
    if (tid >= 512 && tid < 512 + W2) {
        int row = tid - 512;
        float l[32];
        #pragma unroll
        for (int j = 0; j < 32; j++) {
            float s = Ls[j * LSTP + row];
            #pragma unroll
            for (int m = 0; m < 32; m++)
                if (m < j) s -= l[m] * Dg[m * 33 + j];
            l[j] = s * invd[j];
        }
        #pragma unroll
        for (int j = 0; j < 32; j++)
            Ls[j * LSTP + row] = l[j];
    }
    __syncthreads();
    // L21 writeback (coalesced)
    for (int row = r5; row < W2; row += 32)
        A[(c0 + 32 + row) * 512 + c0 + c5] = Ls[c5 * LSTP + row];
}

// ---------------- K5t: trailing update [A22|Z] -= L21 * [U12|Y] ----------------
__global__ __launch_bounds__(256) void k5t_trail(float* __restrict__ aug, int c0) {
    __shared__ __align__(16) float Lt[32][36];
    __shared__ __align__(16) float Ut[32][36];
    int b = blockIdx.z, tid = threadIdx.x;
    float* A = aug + (size_t)b * 256 * 512;
    int r0  = c0 + 32 + blockIdx.x * 32;
    int cc0 = c0 + 32 + blockIdx.y * 32;
    int lr = tid >> 3, lc = (tid & 7) * 4;
    *(float4*)&Lt[lr][lc] = *(const float4*)&A[(size_t)(r0 + lr) * 512 + c0 + lc];
    *(float4*)&Ut[lr][lc] = *(const float4*)&A[(size_t)(c0 + lr) * 512 + cc0 + lc];
    __syncthreads();
    float* gp = &A[(size_t)(r0 + lr) * 512 + cc0 + lc];
    float4 acc = *(const float4*)gp;
    #pragma unroll
    for (int k = 0; k < 32; k++) {
        float lv = Lt[lr][k];
        float4 uv = *(const float4*)&Ut[k][lc];
        acc.x -= lv * uv.x;
        acc.y -= lv * uv.y;
        acc.z -= lv * uv.z;
        acc.w -= lv * uv.w;
    }
    *(float4*)gp = acc;
}

// ---------------- K5s: BACKWARD substitution only (U X = Y), 64 cols/block ----------------
#define ZST  68
#define LBST 36

__global__ __launch_bounds__(512, 2) void k5s_solve(float* __restrict__ aug) {
    __shared__ __align__(16) float Zs[256 * ZST];   // 69.6 KB: RHS block
    __shared__ __align__(16) float Lb[224 * LBST];  // 32.3 KB: U strip above
    __shared__ __align__(16) float Dg[32 * 33];
    __shared__ float invd[32];
    int b = blockIdx.y, tid = threadIdx.x;
    float* A = aug + (size_t)b * 256 * 512;
    int cb = blockIdx.x * 64;
    int c = tid & 63, g = tid >> 6;       // g in 0..7
    int rr = tid >> 5, cc = tid & 31;

    // load the 256x64 Y block
    for (int r = g; r < 256; r += 8)
        Zs[r * ZST + c] = A[r * 512 + 256 + cb + c];

    for (int p = 7; p >= 0; p--) {
        int c0 = 32 * p, na = c0;
        for (int r = rr; r < 32; r += 16)
            Dg[r * 33 + cc] = A[(c0 + r) * 512 + c0 + cc];
        for (int r = rr; r < na; r += 16)
            Lb[r * LBST + cc] = A[r * 512 + c0 + cc];
        if (tid < 32)   // diag reciprocal from global (independent of Dg staging)
            invd[tid] = 1.0f / A[(c0 + tid) * 512 + c0 + tid];
        __syncthreads();
        // 32x32 upper back-solve, one thread per RHS column
        if (tid < 64) {
            float x[32];
            #pragma unroll
            for (int j = 31; j >= 0; j--) {
                float s = Zs[(c0 + j) * ZST + tid];
                #pragma unroll
                for (int m = 0; m < 32; m++)
                    if (m > j) s -= Dg[j * 33 + m] * x[m];
                x[j] = s * invd[j];
            }
            #pragma unroll
            for (int j = 0; j < 32; j++) Zs[(c0 + j) * ZST + tid] = x[j];
        }
        __syncthreads();
        if (na > 0) {
            // panel x values for this thread's column -> registers
            float z[32];
            #pragma unroll
            for (int k = 0; k < 32; k++) z[k] = Zs[(c0 + k) * ZST + c];
            for (int r = g; r < na; r += 8) {
                const float* lp = &Lb[r * LBST];
                float a0 = 0.f, a1 = 0.f, a2 = 0.f, a3 = 0.f;
                #pragma unroll
                for (int k = 0; k < 32; k += 4) {
                    float4 lv = *(const float4*)(lp + k);
                    a0 += lv.x * z[k + 0];
                    a1 += lv.y * z[k + 1];
                    a2 += lv.z * z[k + 2];
                    a3 += lv.w * z[k + 3];
                }
                Zs[r * ZST + c] -= (a0 + a1) + (a2 + a3);
            }
        }
        __syncthreads();
    }

    // store M1 back to aug right half
    for (int r = g; r < 256; r += 8)
        A[r * 512 + 256 + cb + c] = Zs[r * ZST + c];
}

// ---------------- K6: W[f][e] = sum_y Yc[y][f] * M1[y][e] / 256 ----------------
__global__ __launch_bounds__(256) void k6_w(const float* __restrict__ Yc,
                                            const float* __restrict__ aug,
                                            float* __restrict__ W) {
    __shared__ float As[16][68];
    __shared__ float Bs[16][68];
    int tid = threadIdx.x;
    int m0 = blockIdx.x * 64, n0 = blockIdx.y * 64, b = blockIdx.z;
    const float* Ycb = Yc + (size_t)b * YD * ENSN;
    const float* augb = aug + (size_t)b * YD * 512;
    int tr = tid >> 4, tc = tid & 15;
    float acc[4][4];
    #pragma unroll
    for (int i = 0; i < 4; i++)
        #pragma unroll
        for (int j = 0; j < 4; j++) acc[i][j] = 0.f;
    int c = tid & 63, kr0 = tid >> 6;
    for (int k0 = 0; k0 < YD; k0 += 16) {
        #pragma unroll
        for (int p = 0; p < 4; p++) {
            int kk = kr0 + p * 4;
            As[kk][c] = Ycb[(k0 + kk) * ENSN + m0 + c];
            Bs[kk][c] = augb[(k0 + kk) * 512 + 256 + n0 + c];
        }
        __syncthreads();
        #pragma unroll
        for (int kk = 0; kk < 16; kk++) {
            float4 a = *(const float4*)&As[kk][tr * 4];
            float4 bb = *(const float4*)&Bs[kk][tc * 4];
            float af[4] = {a.x, a.y, a.z, a.w};
            float bf[4] = {bb.x, bb.y, bb.z, bb.w};
            #pragma unroll
            for (int i = 0; i < 4; i++)
                #pragma unroll
                for (int j = 0; j < 4; j++) acc[i][j] += af[i] * bf[j];
        }
        __syncthreads();
    }
    float* Wb = W + (size_t)b * ENSN * ENSN;
    #pragma unroll
    for (int i = 0; i < 4; i++)
        #pragma unroll
        for (int j = 0; j < 4; j++)
            Wb[(m0 + tr * 4 + i) * ENSN + n0 + tc * 4 + j] = acc[i][j] * (1.0f / ENSN);
}

// ---------------- K7: out[b,e,x] = Ens[b,e,x] + sum_f W[f][e]*(Ens[b,f,x]-x_m[b,x]) ----------------
__global__ __launch_bounds__(256, 4) void k7_update(const float* __restrict__ E,
                                                    const float* __restrict__ W,
                                                    const float* __restrict__ xm,
                                                    float* __restrict__ out) {
    __shared__ float As[16][260];
    __shared__ float Bs[16][68];
    __shared__ float xs[64];
    int tid = threadIdx.x;
    int x0 = blockIdx.x * 64;
    int b = blockIdx.y;
    const float* Wb = W + (size_t)b * ENSN * ENSN;
    const float* Eb = E + (size_t)b * ENSN * XDIM;
    if (tid < 64) xs[tid] = xm[b * XDIM + x0 + tid];
    __syncthreads();
    int tr = tid >> 4, tc = tid & 15;
    float acc[16][4];
    #pragma unroll
    for (int i = 0; i < 16; i++)
        #pragma unroll
        for (int j = 0; j < 4; j++) acc[i][j] = 0.f;
    for (int k0 = 0; k0 < ENSN; k0 += 16) {
        #pragma unroll
        for (int p = 0; p < 16; p++)
            As[p][tid] = Wb[(k0 + p) * ENSN + tid];
        #pragma unroll
        for (int p = 0; p < 4; p++) {
            int kk = (tid >> 6) + p * 4;
            int cc = tid & 63;
            Bs[kk][cc] = Eb[(size_t)(k0 + kk) * XDIM + x0 + cc] - xs[cc];
        }
        __syncthreads();
        #pragma unroll
        for (int kk = 0; kk < 16; kk++) {
            float4 bv = *(const float4*)&Bs[kk][tc * 4];
            float bf[4] = {bv.x, bv.y, bv.z, bv.w};
            #pragma unroll
            for (int q = 0; q < 4; q++) {
                float4 av = *(const float4*)&As[kk][tr * 16 + q * 4];
                float af[4] = {av.x, av.y, av.z, av.w};
                #pragma unroll
                for (int c2 = 0; c2 < 4; c2++)
                    #pragma unroll
                    for (int j = 0; j < 4; j++)
                        acc[q * 4 + c2][j] += af[c2] * bf[j];
            }
        }
        __syncthreads();
    }
    #pragma unroll
    for (int i = 0; i < 16; i++) {
        int e = tr * 16 + i;
        size_t idx = (size_t)(b * ENSN + e) * XDIM + x0 + tc * 4;
        float4 ev = *(const float4*)&E[idx];
        float4 ov;
        ov.x = ev.x + acc[i][0];
        ov.y = ev.y + acc[i][1];
        ov.z = ev.z + acc[i][2];
        ov.w = ev.w + acc[i][3];
        *(float4*)&out[idx] = ov;
    }
}

extern "C" void kernel_launch(void* const* d_in, const int* in_sizes, int n_in,
                              void* d_out, int out_size, void* d_ws, size_t ws_size,
                              hipStream_t stream) {
    const float* Ens   = (const float*)d_in[0];  // [8,256,8192]
    const float* H     = (const float*)d_in[1];  // [8192,256]
    const float* ytm   = (const float*)d_in[2];  // [1,256]
    const float* ystd  = (const float*)d_in[3];  // [1,256]
    const float* noise = (const float*)d_in[4];  // [8,256,256]
    float* out = (float*)d_out;
    float* ws  = (float*)d_ws;

    float* Y   = ws + OFF_Y;
    float* Yc  = ws + OFF_YC;
    float* aug = ws + OFF_AUG;
    float* W   = ws + OFF_W;
    float* xm  = ws + OFF_XM;

    hipMemsetAsync(Y, 0, (size_t)2048 * 256 * sizeof(float), stream);

    k1_colmean<<<dim3(XDIM / 256, BATCH), 256, 0, stream>>>(Ens, xm);
    k2_ygemm<<<dim3(16, 4, K2SPLIT), 256, 0, stream>>>(Ens, H, Y);
    k3_center<<<dim3(4, BATCH), 256, 0, stream>>>(Y, ytm, ystd, noise, Yc, aug);
    k4_cyy<<<dim3(4, 4, BATCH), 256, 0, stream>>>(Yc, ystd, aug);
    for (int p = 0; p < 8; p++) {
        k5p_panel<<<dim3(BATCH), 1024, 0, stream>>>(aug, 32 * p);
        if (p < 7)
            k5t_trail<<<dim3(7 - p, 15 - p, BATCH), 256, 0, stream>>>(aug, 32 * p);
    }
    k5s_solve<<<dim3(4, BATCH), 512, 0, stream>>>(aug);
    k6_w<<<dim3(4, 4, BATCH), 256, 0, stream>>>(Yc, aug, W);
    k7_update<<<dim3(XDIM / 64, BATCH), 256, 0, stream>>>(Ens, W, xm, out);
}